// Round 1
// baseline (3754.552 us; speedup 1.0000x reference)
//
#include <hip/hip_runtime.h>
#include <hip/hip_bf16.h>

#define VV 50257
#define DD 512
#define TT 1024
#define VPADN 50304   // 393*128
#define NB 16

typedef __bf16 bf16;
typedef __attribute__((ext_vector_type(8))) __bf16 bf16x8;
typedef __attribute__((ext_vector_type(4))) float f32x4;

__device__ __forceinline__ void gload_lds16(const void* g, void* l) {
  __builtin_amdgcn_global_load_lds(
      (__attribute__((address_space(1))) void*)(void*)g,
      (__attribute__((address_space(3))) void*)l, 16, 0, 0);
}

// ---------------- phase 1: gate-input gather  X[t][gate][d] = W_i*[d, tok] + b ----------------
__global__ void embed_kernel(const int* __restrict__ idx,
                             const float* __restrict__ Wii, const float* __restrict__ Wif,
                             const float* __restrict__ Wio, const float* __restrict__ Wig,
                             const float* __restrict__ bi, const float* __restrict__ bfv,
                             const float* __restrict__ bo, const float* __restrict__ bg,
                             float* __restrict__ X) {
  int t = blockIdx.x;
  int d = threadIdx.x;          // 512 threads
  int tok = idx[t];
  X[(size_t)(t*4 + 0)*DD + d] = Wii[(size_t)d*VV + tok] + bi[d];
  X[(size_t)(t*4 + 1)*DD + d] = Wif[(size_t)d*VV + tok] + bfv[d];
  X[(size_t)(t*4 + 2)*DD + d] = Wio[(size_t)d*VV + tok] + bo[d];
  X[(size_t)(t*4 + 3)*DD + d] = Wig[(size_t)d*VV + tok] + bg[d];
}

// ---------------- phase 1b: W_out f32 -> bf16 (padded to VPADN rows) ----------------
__global__ void wconv_kernel(const float* __restrict__ Wout, bf16* __restrict__ Wbf) {
  size_t total = (size_t)VPADN * DD;
  for (size_t i = (size_t)blockIdx.x*blockDim.x + threadIdx.x; i < total;
       i += (size_t)gridDim.x*blockDim.x) {
    size_t vp = i >> 9;  // /512
    float x = (vp < VV) ? Wout[i] : 0.f;
    Wbf[i] = (bf16)x;
  }
}

// ---------------- phase 2: sequential LSTM recurrence, 16 blocks, flag sync ----------------
// block b owns h-dims [b*32, b*32+32)  -> 128 gate rows (gate-major)
// thread: rg = tid>>4 (4 rows rg*4..rg*4+3), cs = tid&15 (cols cs*4 + 64*jj + e)
__global__ __launch_bounds__(512, 2) void recur_kernel(
    const float* __restrict__ X,
    const float* __restrict__ Whi, const float* __restrict__ Whf,
    const float* __restrict__ Who, const float* __restrict__ Whg,
    float* __restrict__ Hf32, bf16* __restrict__ Hbf,
    int* __restrict__ flags, float* __restrict__ out_tail) {
  __shared__ float hsh[DD];
  __shared__ float gact[128];
  __shared__ float cst[32];
  const int b = blockIdx.x, tid = threadIdx.x;
  const int rg = tid >> 4, cs = tid & 15;
  const int lr0 = rg << 2;
  const int gate = lr0 >> 5;
  const float* Wg = (gate == 0) ? Whi : (gate == 1) ? Whf : (gate == 2) ? Who : Whg;
  const int col0 = cs << 2;

  f32x4 w[4][8];
  for (int r = 0; r < 4; ++r) {
    int hdim = (b << 5) + ((lr0 + r) & 31);
    const float* wr_ = &Wg[(size_t)hdim*DD + col0];
    #pragma unroll
    for (int jj = 0; jj < 8; ++jj)
      w[r][jj] = *(const f32x4*)(wr_ + 64*jj);
  }
  if (tid < 32) cst[tid] = 0.f;

  for (int t = 0; t < TT; ++t) {
    // prefetch gate inputs (leaders only) -- independent of h, hides under sync
    float xv[4];
    if (cs == 0) {
      #pragma unroll
      for (int r = 0; r < 4; ++r) {
        int hdim = (b << 5) + ((lr0 + r) & 31);
        xv[r] = X[(size_t)((t << 2) + gate)*DD + hdim];
      }
    }
    if (t > 0) {
      if (tid < NB) {
        while (__hip_atomic_load(&flags[tid], __ATOMIC_ACQUIRE, __HIP_MEMORY_SCOPE_AGENT) < t) {}
      }
      __syncthreads();
      hsh[tid] = __hip_atomic_load(&Hf32[(size_t)(t-1)*DD + tid], __ATOMIC_RELAXED,
                                   __HIP_MEMORY_SCOPE_AGENT);
    } else {
      hsh[tid] = 0.f;
    }
    __syncthreads();

    float acc[4] = {0.f, 0.f, 0.f, 0.f};
    #pragma unroll
    for (int jj = 0; jj < 8; ++jj) {
      f32x4 h4 = *(const f32x4*)&hsh[col0 + 64*jj];
      #pragma unroll
      for (int r = 0; r < 4; ++r) {
        acc[r] = fmaf(w[r][jj][0], h4[0], acc[r]);
        acc[r] = fmaf(w[r][jj][1], h4[1], acc[r]);
        acc[r] = fmaf(w[r][jj][2], h4[2], acc[r]);
        acc[r] = fmaf(w[r][jj][3], h4[3], acc[r]);
      }
    }
    #pragma unroll
    for (int mask = 1; mask < 16; mask <<= 1)
      #pragma unroll
      for (int r = 0; r < 4; ++r)
        acc[r] += __shfl_xor(acc[r], mask);

    if (cs == 0) {
      #pragma unroll
      for (int r = 0; r < 4; ++r) {
        float pre = acc[r] + xv[r];
        gact[lr0 + r] = (gate < 3) ? (1.f/(1.f + expf(-pre))) : tanhf(pre);
      }
    }
    __syncthreads();

    if (tid < 32) {
      float iv = gact[tid], fv = gact[32 + tid], ov = gact[64 + tid], gv = gact[96 + tid];
      float c = fv*cst[tid] + iv*gv;
      cst[tid] = c;
      float h = ov*tanhf(c);
      int hd = (b << 5) + tid;
      __hip_atomic_store(&Hf32[(size_t)t*DD + hd], h, __ATOMIC_RELAXED,
                         __HIP_MEMORY_SCOPE_AGENT);
      Hbf[(size_t)t*DD + hd] = (bf16)h;
      if (t == TT - 1) { out_tail[hd] = h; out_tail[DD + hd] = c; }
    }
    __syncthreads();
    if (tid == 0) {
      __threadfence();
      __hip_atomic_store(&flags[b], t + 1, __ATOMIC_RELEASE, __HIP_MEMORY_SCOPE_AGENT);
    }
  }
}

// ---------------- phase 3: logits = Hbf[1024x512] @ Wbf^T[50304x512] + b_out ----------------
__global__ __launch_bounds__(256, 2) void gemm_kernel(
    const bf16* __restrict__ A, const bf16* __restrict__ B,
    const float* __restrict__ bout, float* __restrict__ Cout) {
  __shared__ bf16 As[128*32];
  __shared__ bf16 Bs[128*32];
  const int tid = threadIdx.x;
  const int n0 = blockIdx.x * 128, m0 = blockIdx.y * 128;
  const int w = tid >> 6, l = tid & 63;
  const int wr = w >> 1, wc = w & 1;
  f32x4 acc[4][4] = {};

  for (int k0 = 0; k0 < DD; k0 += 32) {
    #pragma unroll
    for (int c = 0; c < 2; ++c) {
      int j = c*256 + tid;
      int row = j >> 2, kc = (j & 3) << 3;
      gload_lds16(&A[(size_t)(m0 + row)*DD + k0 + kc], (char*)As + (c*4096 + w*1024));
      gload_lds16(&B[(size_t)(n0 + row)*DD + k0 + kc], (char*)Bs + (c*4096 + w*1024));
    }
    __syncthreads();
    bf16x8 af[4], bfr[4];
    #pragma unroll
    for (int mi = 0; mi < 4; ++mi)
      af[mi] = *(const bf16x8*)&As[(wr*64 + mi*16 + (l & 15))*32 + (l >> 4)*8];
    #pragma unroll
    for (int ni = 0; ni < 4; ++ni)
      bfr[ni] = *(const bf16x8*)&Bs[(wc*64 + ni*16 + (l & 15))*32 + (l >> 4)*8];
    #pragma unroll
    for (int mi = 0; mi < 4; ++mi)
      #pragma unroll
      for (int ni = 0; ni < 4; ++ni)
        acc[mi][ni] = __builtin_amdgcn_mfma_f32_16x16x32_bf16(af[mi], bfr[ni], acc[mi][ni], 0, 0, 0);
    __syncthreads();
  }

  #pragma unroll
  for (int mi = 0; mi < 4; ++mi) {
    int rbase = m0 + wr*64 + mi*16 + (l >> 4)*4;
    #pragma unroll
    for (int ni = 0; ni < 4; ++ni) {
      int col = n0 + wc*64 + ni*16 + (l & 15);
      if (col < VV) {
        float bb = bout[col];
        #pragma unroll
        for (int r = 0; r < 4; ++r)
          Cout[(size_t)(rbase + r)*VV + col] = acc[mi][ni][r] + bb;
      }
    }
  }
}

// ---------------- phase 4: in-place row log_softmax ----------------
__global__ __launch_bounds__(256) void lsm_kernel(float* __restrict__ logits) {
  const int t = blockIdx.x, tid = threadIdx.x;
  float* row = logits + (size_t)t*VV;
  float m = -INFINITY, s = 0.f;
  for (int v = tid; v < VV; v += 256) {
    float x = row[v];
    float nm = fmaxf(m, x);
    s = s*expf(m - nm) + expf(x - nm);
    m = nm;
  }
  #pragma unroll
  for (int mask = 1; mask < 64; mask <<= 1) {
    float om = __shfl_xor(m, mask);
    float os = __shfl_xor(s, mask);
    float nm = fmaxf(m, om);
    s = s*expf(m - nm) + os*expf(om - nm);
    m = nm;
  }
  __shared__ float sm[4], ss[4], lse_sh;
  int wv = tid >> 6;
  if ((tid & 63) == 0) { sm[wv] = m; ss[wv] = s; }
  __syncthreads();
  if (tid == 0) {
    float M = sm[0], S = ss[0];
    for (int i2 = 1; i2 < 4; ++i2) {
      float nm = fmaxf(M, sm[i2]);
      S = S*expf(M - nm) + ss[i2]*expf(sm[i2] - nm);
      M = nm;
    }
    lse_sh = M + logf(S);
  }
  __syncthreads();
  float lse = lse_sh;
  for (int v = tid; v < VV; v += 256)
    row[v] -= lse;
}

extern "C" void kernel_launch(void* const* d_in, const int* in_sizes, int n_in,
                              void* d_out, int out_size, void* d_ws, size_t ws_size,
                              hipStream_t stream) {
  const int*   idx  = (const int*)d_in[0];
  const float* Wii  = (const float*)d_in[1];
  const float* Wif  = (const float*)d_in[2];
  const float* Wio  = (const float*)d_in[3];
  const float* Wig  = (const float*)d_in[4];
  const float* Whi  = (const float*)d_in[5];
  const float* Whf  = (const float*)d_in[6];
  const float* Who  = (const float*)d_in[7];
  const float* Whg  = (const float*)d_in[8];
  const float* bi   = (const float*)d_in[9];
  const float* bfv  = (const float*)d_in[10];
  const float* bo   = (const float*)d_in[11];
  const float* bg   = (const float*)d_in[12];
  const float* Wout = (const float*)d_in[13];
  const float* bout = (const float*)d_in[14];
  float* out = (float*)d_out;

  char* ws = (char*)d_ws;
  float* X    = (float*)ws;                              // 8,388,608 B
  float* Hf32 = (float*)(ws + 8388608);                  // 2,097,152 B
  bf16*  Hbf  = (bf16*)(ws + 8388608 + 2097152);         // 1,048,576 B
  bf16*  Wbf  = (bf16*)(ws + 11534336);                  // 51,511,296 B
  int*   flags= (int*)(ws + 11534336 + 51511296);        // 256 B  (total ~63.05 MB)

  hipMemsetAsync(flags, 0, 256, stream);
  embed_kernel<<<TT, 512, 0, stream>>>(idx, Wii, Wif, Wio, Wig, bi, bfv, bo, bg, X);
  wconv_kernel<<<2048, 256, 0, stream>>>(Wout, Wbf);
  recur_kernel<<<NB, 512, 0, stream>>>(X, Whi, Whf, Who, Whg, Hf32, Hbf, flags,
                                       out + (size_t)TT*VV);
  gemm_kernel<<<dim3(393, 8), 256, 0, stream>>>(Hbf, Wbf, bout, out);
  lsm_kernel<<<TT, 256, 0, stream>>>(out);
}